// Round 6
// baseline (281.971 us; speedup 1.0000x reference)
//
#include <hip/hip_runtime.h>
#include <math.h>

#define B_    4
#define CDIM  512
#define HEADS 8
#define HD    64
#define NN    4096
#define QSZ   ((size_t)B_*HEADS*NN*HD)   // 8388608 elements
// q scale folded with log2(e): 0.125 * 1.4426950408889634
#define SCALE_Q 0.18033688011112042f

typedef __attribute__((ext_vector_type(8))) short short8;   // 8 bf16
typedef __attribute__((ext_vector_type(4))) float f32x4;
typedef __attribute__((ext_vector_type(16))) float f32x16;
union U4S8 { uint4 u; short8 s; };

// RNE fp32 -> bf16
__device__ inline unsigned pk(float a, float b) {
    unsigned ua = __float_as_uint(a), ub = __float_as_uint(b);
    ua += 0x7FFFu + ((ua >> 16) & 1u);
    ub += 0x7FFFu + ((ub >> 16) & 1u);
    return (ua >> 16) | (ub & 0xFFFF0000u);
}
__device__ inline unsigned short bf16_1(float a) {
    unsigned ua = __float_as_uint(a);
    ua += 0x7FFFu + ((ua >> 16) & 1u);
    return (unsigned short)(ua >> 16);
}
// single-instruction packed f32->bf16 (RNE); S0 -> low16, S1 -> high16
__device__ inline unsigned cvtpk(float a, float b) {
    unsigned r;
    asm("v_cvt_pk_bf16_f32 %0, %1, %2" : "=v"(r) : "v"(a), "v"(b));
    return r;
}

__device__ inline void load_lds16(const unsigned short* g, unsigned short* l) {
    __builtin_amdgcn_global_load_lds(
        (const __attribute__((address_space(1))) unsigned int*)g,
        (__attribute__((address_space(3))) unsigned int*)l, 16, 0, 0);
}

// ------------------------------------------------------- weights -> bf16
// wq: 1536x512 (first 512 rows = q, pre-scaled by SCALE_Q); wp: 512x512
__global__ void conv_w_kernel(const float* __restrict__ wq, const float* __restrict__ wp,
                              unsigned short* __restrict__ wqb, unsigned short* __restrict__ wpb) {
    int id = blockIdx.x * 256 + threadIdx.x;
    const float* src; unsigned short* dst; size_t off; float sc = 1.0f;
    if (id < 98304) { src = wq; dst = wqb; off = (size_t)id * 8; if (off < 262144) sc = SCALE_Q; }
    else            { src = wp; dst = wpb; off = (size_t)(id - 98304) * 8; }
    float4 a = *(const float4*)(src + off);
    float4 b = *(const float4*)(src + off + 4);
    uint4 u;
    u.x = pk(a.x * sc, a.y * sc); u.y = pk(a.z * sc, a.w * sc);
    u.z = pk(b.x * sc, b.y * sc); u.w = pk(b.z * sc, b.w * sc);
    *(uint4*)(dst + off) = u;
}

// ------------------------------------------------------- rope tables [j][n]
__global__ void rope_table_kernel(float* __restrict__ ct, float* __restrict__ st) {
    int id = blockIdx.x * 256 + threadIdx.x;
    int j = id >> 12, n = id & 4095;
    int i = j & 15;
    float pos = (j < 16) ? (float)(n >> 6) : (float)(n & 63);
    float freq = exp2f(-(float)i * 0.8304820237218406f);  // 10000^(-i/16)
    float ang = pos * freq;
    ct[id] = cosf(ang);
    st[id] = sinf(ang);
}

// ------------------------------------------------------- x transpose+convert
__global__ __launch_bounds__(256) void transpose_x_kernel(
        const float* __restrict__ x, unsigned short* __restrict__ xt) {
    __shared__ unsigned short T[64 * 72];
    int t = threadIdx.x;
    int b = blockIdx.z, c0 = blockIdx.y * 64, n0 = blockIdx.x * 64;
    const float* xb = x + ((size_t)b * CDIM + c0) * NN + n0;
    int crow = t >> 2, nseg = t & 3;
#pragma unroll
    for (int g = 0; g < 4; ++g) {
        float4 f = *(const float4*)(xb + (size_t)crow * NN + nseg * 16 + g * 4);
        int nb = nseg * 16 + g * 4;
        T[(nb + 0) * 72 + crow] = bf16_1(f.x);
        T[(nb + 1) * 72 + crow] = bf16_1(f.y);
        T[(nb + 2) * 72 + crow] = bf16_1(f.z);
        T[(nb + 3) * 72 + crow] = bf16_1(f.w);
    }
    __syncthreads();
    unsigned short* xo = xt + ((size_t)b * NN + n0) * CDIM + c0;
    int nrow = t >> 2, cseg = t & 3;
    uint4 u0 = *(uint4*)(T + nrow * 72 + cseg * 16);
    uint4 u1 = *(uint4*)(T + nrow * 72 + cseg * 16 + 8);
    *(uint4*)(xo + (size_t)nrow * CDIM + cseg * 16)     = u0;
    *(uint4*)(xo + (size_t)nrow * CDIM + cseg * 16 + 8) = u1;
}

// ------------------------------------------------------- qkv MFMA GEMM
__global__ __launch_bounds__(256, 2) void qkv_mfma_kernel(
        const unsigned short* __restrict__ xt, const unsigned short* __restrict__ wq,
        unsigned short* __restrict__ qbf, unsigned short* __restrict__ kbf,
        unsigned short* __restrict__ vt,
        const float* __restrict__ ct, const float* __restrict__ st) {
    __shared__ unsigned short smem[8192];
    int t = threadIdx.x;
    int lane = t & 63, w = t >> 6;
    int qlo = lane & 15, quad = lane >> 4;
    int b = blockIdx.z, o0 = blockIdx.y * 128, n0 = blockIdx.x * 128;
    const unsigned short* xb = xt + (size_t)b * NN * CDIM;
    int row = t >> 2, seg = t & 3;
    int wn = (w & 1) * 64, wo = (w >> 1) * 64;

    f32x4 acc[4][4];
#pragma unroll
    for (int i = 0; i < 4; ++i)
#pragma unroll
        for (int j = 0; j < 4; ++j) acc[i][j] = f32x4{0.f, 0.f, 0.f, 0.f};

    for (int k0 = 0; k0 < 512; k0 += 32) {
        __syncthreads();
        load_lds16(xb + (size_t)(n0 + row) * 512 + k0 + seg * 8,        smem + t * 8);
        load_lds16(xb + (size_t)(n0 + 64 + row) * 512 + k0 + seg * 8,   smem + 2048 + t * 8);
        load_lds16(wq + (size_t)(o0 + row) * 512 + k0 + seg * 8,        smem + 4096 + t * 8);
        load_lds16(wq + (size_t)(o0 + 64 + row) * 512 + k0 + seg * 8,   smem + 6144 + t * 8);
        __syncthreads();
        U4S8 af[4], bf[4];
#pragma unroll
        for (int mt = 0; mt < 4; ++mt)
            af[mt].u = *(const uint4*)(smem + (wn + 16 * mt + qlo) * 32 + quad * 8);
#pragma unroll
        for (int nt = 0; nt < 4; ++nt)
            bf[nt].u = *(const uint4*)(smem + 4096 + (wo + 16 * nt + qlo) * 32 + quad * 8);
#pragma unroll
        for (int mt = 0; mt < 4; ++mt)
#pragma unroll
            for (int nt = 0; nt < 4; ++nt)
                acc[mt][nt] = __builtin_amdgcn_mfma_f32_16x16x32_bf16(
                    af[mt].s, bf[nt].s, acc[mt][nt], 0, 0, 0);
    }

    int og = o0 + wo;
    int s = og >> 9;
    int h = (og & 511) >> 6;
    int bh = b * HEADS + h;
    if (s < 2) {
        unsigned short* dst = (s ? kbf : qbf) + (size_t)bh * NN * HD;
#pragma unroll
        for (int mt = 0; mt < 4; ++mt) {
            int nbase = n0 + wn + 16 * mt + 4 * quad;
#pragma unroll
            for (int ntp = 0; ntp < 2; ++ntp) {
                int j = 16 * ntp + qlo;
                float4 c4 = *(const float4*)(ct + (size_t)j * NN + nbase);
                float4 s4 = *(const float4*)(st + (size_t)j * NN + nbase);
                float cc[4] = {c4.x, c4.y, c4.z, c4.w};
                float ss[4] = {s4.x, s4.y, s4.z, s4.w};
#pragma unroll
                for (int r = 0; r < 4; ++r) {
                    float x1 = acc[mt][ntp][r], x2 = acc[mt][ntp + 2][r];
                    size_t base = (size_t)(nbase + r) * HD;
                    dst[base + j]      = bf16_1(x1 * cc[r] - x2 * ss[r]);
                    dst[base + j + 32] = bf16_1(x1 * ss[r] + x2 * cc[r]);
                }
            }
        }
    } else {
        unsigned short* dst = vt + (size_t)bh * HD * NN;
#pragma unroll
        for (int mt = 0; mt < 4; ++mt)
#pragma unroll
            for (int nt = 0; nt < 4; ++nt) {
                int d = 16 * nt + qlo;
                int n = n0 + wn + 16 * mt + 4 * quad;
                uint2 u;
                u.x = pk(acc[mt][nt][0], acc[mt][nt][1]);
                u.y = pk(acc[mt][nt][2], acc[mt][nt][3]);
                *(uint2*)(dst + (size_t)d * NN + n) = u;
            }
    }
}

// exp2 + pack one 8-value group of an S tile into a PV A-frag, accumulating L
#define EXP_GRP(Sv, MTQ, KSL, PA)                                        \
    {                                                                    \
        float p0 = __builtin_amdgcn_exp2f(Sv[8 * (KSL) + 0]);            \
        float p1 = __builtin_amdgcn_exp2f(Sv[8 * (KSL) + 1]);            \
        float p2 = __builtin_amdgcn_exp2f(Sv[8 * (KSL) + 2]);            \
        float p3 = __builtin_amdgcn_exp2f(Sv[8 * (KSL) + 3]);            \
        float p4 = __builtin_amdgcn_exp2f(Sv[8 * (KSL) + 4]);            \
        float p5 = __builtin_amdgcn_exp2f(Sv[8 * (KSL) + 5]);            \
        float p6 = __builtin_amdgcn_exp2f(Sv[8 * (KSL) + 6]);            \
        float p7 = __builtin_amdgcn_exp2f(Sv[8 * (KSL) + 7]);            \
        Lsum[MTQ] += ((p0 + p1) + (p2 + p3)) + ((p4 + p5) + (p6 + p7));  \
        PA.u.x = cvtpk(p0, p1); PA.u.y = cvtpk(p2, p3);                  \
        PA.u.z = cvtpk(p4, p5); PA.u.w = cvtpk(p6, p7);                  \
    }

#define MFMA32(A, B, C) __builtin_amdgcn_mfma_f32_32x32x16_bf16((A), (B), (C), 0, 0, 0)

// one pipeline half-step: QK(subtile s) -> SPROD, exp(SCONS = S(s-1)) -> pa,
// PV(s-1) from (VBASE, VHALF).  KBASE/KHALF locate subtile s's K rows.
#define HALF_STEP(SCONS, SPROD, KBASE, KHALF, VBASE, VHALF)                              \
    {                                                                                    \
        U4S8 ka0, ka1, ka2, ka3;                                                         \
        ka0.u = *(const uint4*)((KBASE) + ((KHALF) * 32 + l31) * 144 + 16 * h);          \
        ka1.u = *(const uint4*)((KBASE) + ((KHALF) * 32 + l31) * 144 + 32 + 16 * h);     \
        ka2.u = *(const uint4*)((KBASE) + ((KHALF) * 32 + l31) * 144 + 64 + 16 * h);     \
        ka3.u = *(const uint4*)((KBASE) + ((KHALF) * 32 + l31) * 144 + 96 + 16 * h);     \
        U4S8 pa[2][2];                                                                   \
        SPROD[0] = MFMA32(ka0.s, qf[0][0].s, Zv);                                        \
        SPROD[1] = MFMA32(ka0.s, qf[1][0].s, Zv);                                        \
        EXP_GRP(SCONS[0], 0, 0, pa[0][0]);                                               \
        SPROD[0] = MFMA32(ka1.s, qf[0][1].s, SPROD[0]);                                  \
        SPROD[1] = MFMA32(ka1.s, qf[1][1].s, SPROD[1]);                                  \
        EXP_GRP(SCONS[0], 0, 1, pa[1][0]);                                               \
        SPROD[0] = MFMA32(ka2.s, qf[0][2].s, SPROD[0]);                                  \
        SPROD[1] = MFMA32(ka2.s, qf[1][2].s, SPROD[1]);                                  \
        EXP_GRP(SCONS[1], 1, 0, pa[0][1]);                                               \
        SPROD[0] = MFMA32(ka3.s, qf[0][3].s, SPROD[0]);                                  \
        SPROD[1] = MFMA32(ka3.s, qf[1][3].s, SPROD[1]);                                  \
        EXP_GRP(SCONS[1], 1, 1, pa[1][1]);                                               \
        { U4S8 vb; vb.u = *(const uint4*)((VBASE) + l31 * 144 + (VHALF) * 64 + 16 * h);  \
          O[0][0] = MFMA32(pa[0][0].s, vb.s, O[0][0]);                                   \
          O[1][0] = MFMA32(pa[0][1].s, vb.s, O[1][0]); }                                 \
        { U4S8 vb; vb.u = *(const uint4*)((VBASE) + (32 + l31) * 144 + (VHALF) * 64 + 16 * h); \
          O[0][1] = MFMA32(pa[0][0].s, vb.s, O[0][1]);                                   \
          O[1][1] = MFMA32(pa[0][1].s, vb.s, O[1][1]); }                                 \
        { U4S8 vb; vb.u = *(const uint4*)((VBASE) + l31 * 144 + (VHALF) * 64 + 32 + 16 * h); \
          O[0][0] = MFMA32(pa[1][0].s, vb.s, O[0][0]);                                   \
          O[1][0] = MFMA32(pa[1][1].s, vb.s, O[1][0]); }                                 \
        { U4S8 vb; vb.u = *(const uint4*)((VBASE) + (32 + l31) * 144 + (VHALF) * 64 + 32 + 16 * h); \
          O[0][1] = MFMA32(pa[1][0].s, vb.s, O[0][1]);                                   \
          O[1][1] = MFMA32(pa[1][1].s, vb.s, O[1][1]); }                                 \
    }

// ------------------------------------------------------- attention (MFMA bf16, 32x32x16)
// Triple-buffered K/V LDS + cross-subtile 2-deep software pipeline:
// per 32-key half-step: QK(s) MFMAs || exp(s-1) || PV(s-1).  Every exp
// consumes S produced a full subtile earlier (its MFMAs are long done), and
// every MFMA region has independent VALU beneath it.  3 buffers break the
// WAR hazard: at body c, QK reads buf[c%3] & buf[(c+1)%3], PV(prev) reads
// buf[c%3], staging writes buf[(c+2)%3]; one barrier per 64-key tile.
// Sᵀ=K·Qᵀ; the 32x32 C-layout doubles as the PV A-layout under the key
// permutation "swap bits 2<->3" applied to V at LDS staging.  cvt_pk packs
// P straight into PV A-frags; L on VALU; column-layout L transposed once
// via shfls in the epilogue.  exp2 softmax (log2e folded into q).
// LDS 55296 B.  S rotation is static (SA/SB) to keep regs out of scratch.
__global__ __launch_bounds__(256, 2) void attn_kernel(
        const unsigned short* __restrict__ qbf, const unsigned short* __restrict__ kbf,
        const unsigned short* __restrict__ vt, unsigned short* __restrict__ aot) {
    __shared__ unsigned char smem[55296];     // 3 x (K 64x144 | V 64x144)
    int t = threadIdx.x;
    int lane = t & 63, w = t >> 6;
    int l31 = lane & 31, h = lane >> 5;
    int bb = blockIdx.z, hh = blockIdx.y;
    int bh = bb * HEADS + hh;
    int n0w = blockIdx.x * 256 + w * 64;

    // Q B-frags: qf[mtq][ks]  (col=query=l31, k = 16*ks + 8*h + j)
    U4S8 qf[2][4];
    const unsigned short* qg = qbf + ((size_t)bh * NN + n0w) * HD;
#pragma unroll
    for (int mtq = 0; mtq < 2; ++mtq)
#pragma unroll
        for (int ks = 0; ks < 4; ++ks)
            qf[mtq][ks].u = *(const uint4*)(qg + (size_t)(32 * mtq + l31) * 64 + 16 * ks + 8 * h);

    f32x16 Zv;
#pragma unroll
    for (int i = 0; i < 16; ++i) Zv[i] = 0.f;

    f32x16 O[2][2];
#pragma unroll
    for (int mtq = 0; mtq < 2; ++mtq)
#pragma unroll
        for (int ntd = 0; ntd < 2; ++ntd) O[mtq][ntd] = Zv;
    float Lsum[2] = {0.f, 0.f};              // column sum for query 32*mtq + l31

    const uint4* kg = (const uint4*)kbf + (size_t)bh * NN * 8;
    const uint4* vg = (const uint4*)vt  + (size_t)bh * 64 * 512;

    int rr0 = t >> 3, s8 = t & 7;            // K row / V d-row 0..31 (+32 for second)
    // V permuted in-row byte offset: key-bit2<->bit3 swap at quad granularity
    int voff = 32 * (s8 >> 1) + 8 * (s8 & 1);

    // incremented global pointers (tile stride: K 512 uint4, V 8 uint4)
    const uint4* kp0 = kg + rr0 * 8 + s8;
    const uint4* kp1 = kg + (32 + rr0) * 8 + s8;
    const uint4* vp0 = vg + rr0 * 512 + s8;
    const uint4* vp1 = vg + (32 + rr0) * 512 + s8;

    // per-thread LDS staging destinations (within a buffer)
    unsigned char* kd0 = smem + rr0 * 144 + s8 * 16;
    unsigned char* kd1 = smem + (32 + rr0) * 144 + s8 * 16;
    unsigned char* vd0 = smem + 9216 + rr0 * 144 + voff;
    unsigned char* vd1 = smem + 9216 + (32 + rr0) * 144 + voff;

    // prologue: tiles 0,1 -> buf0,buf1; tile 2 -> regs
    uint4 kr0, kr1, vr0, vr1;
#pragma unroll
    for (int pt = 0; pt < 2; ++pt) {
        kr0 = kp0[0]; kr1 = kp1[0]; vr0 = vp0[0]; vr1 = vp1[0];
        kp0 += 512; kp1 += 512; vp0 += 8; vp1 += 8;
        int bo = pt * 18432;
        *(uint4*)(kd0 + bo) = kr0;
        *(uint4*)(kd1 + bo) = kr1;
        *(uint2*)(vd0 + bo)      = make_uint2(vr0.x, vr0.y);
        *(uint2*)(vd0 + bo + 16) = make_uint2(vr0.z, vr0.w);
        *(uint2*)(vd1 + bo)      = make_uint2(vr1.x, vr1.y);
        *(uint2*)(vd1 + bo + 16) = make_uint2(vr1.z, vr1.w);
    }
    kr0 = kp0[0]; kr1 = kp1[0]; vr0 = vp0[0]; vr1 = vp1[0];
    kp0 += 512; kp1 += 512; vp0 += 8; vp1 += 8;
    __syncthreads();

    // prime: QK(subtile 0) -> SB  (buf0, khalf 0)
    f32x16 SA[2], SB[2];
    {
        U4S8 ka0, ka1, ka2, ka3;
        ka0.u = *(const uint4*)(smem + l31 * 144 + 16 * h);
        ka1.u = *(const uint4*)(smem + l31 * 144 + 32 + 16 * h);
        ka2.u = *(const uint4*)(smem + l31 * 144 + 64 + 16 * h);
        ka3.u = *(const uint4*)(smem + l31 * 144 + 96 + 16 * h);
        SB[0] = MFMA32(ka0.s, qf[0][0].s, Zv);
        SB[1] = MFMA32(ka0.s, qf[1][0].s, Zv);
        SB[0] = MFMA32(ka1.s, qf[0][1].s, SB[0]);
        SB[1] = MFMA32(ka1.s, qf[1][1].s, SB[1]);
        SB[0] = MFMA32(ka2.s, qf[0][2].s, SB[0]);
        SB[1] = MFMA32(ka2.s, qf[1][2].s, SB[1]);
        SB[0] = MFMA32(ka3.s, qf[0][3].s, SB[0]);
        SB[1] = MFMA32(ka3.s, qf[1][3].s, SB[1]);
    }

    int b0 = 0, b1 = 18432, b2 = 36864;      // rotating buffer byte offsets
    for (int c = 0; c < 63; ++c) {
        // ---- stage tile c+2 (in regs) -> buf b2; issue loads for tile c+3
        // (over-reads past the KV stream stay inside the workspace - harmless)
        *(uint4*)(kd0 + b2) = kr0;
        *(uint4*)(kd1 + b2) = kr1;
        *(uint2*)(vd0 + b2)      = make_uint2(vr0.x, vr0.y);
        *(uint2*)(vd0 + b2 + 16) = make_uint2(vr0.z, vr0.w);
        *(uint2*)(vd1 + b2)      = make_uint2(vr1.x, vr1.y);
        *(uint2*)(vd1 + b2 + 16) = make_uint2(vr1.z, vr1.w);
        kr0 = kp0[0]; kr1 = kp1[0]; vr0 = vp0[0]; vr1 = vp1[0];
        kp0 += 512; kp1 += 512; vp0 += 8; vp1 += 8;

        __builtin_amdgcn_s_setprio(1);
        // half1 of tile c:   QK(2c+1)->SA | exp(S(2c)=SB) | PV(2c), V buf b0 half 0
        HALF_STEP(SB, SA, smem + b0, 1, smem + b0 + 9216, 0)
        // half0 of tile c+1: QK(2c+2)->SB | exp(S(2c+1)=SA) | PV(2c+1), V buf b0 half 1
        HALF_STEP(SA, SB, smem + b1, 0, smem + b0 + 9216, 1)
        __builtin_amdgcn_s_setprio(0);

        int tmp = b0; b0 = b1; b1 = b2; b2 = tmp;
        __syncthreads();
    }

    // epilogue: half1 of tile 63 (b0 now = tile 63's buffer)
    HALF_STEP(SB, SA, smem + b0, 1, smem + b0 + 9216, 0)
    // final: exp(S(127)=SA) + PV(127), V buf b0 half 1
    {
        U4S8 pa[2][2];
        EXP_GRP(SA[0], 0, 0, pa[0][0]);
        EXP_GRP(SA[0], 0, 1, pa[1][0]);
        EXP_GRP(SA[1], 1, 0, pa[0][1]);
        EXP_GRP(SA[1], 1, 1, pa[1][1]);
        const unsigned char* vbb = smem + b0 + 9216;
        { U4S8 vb; vb.u = *(const uint4*)(vbb + l31 * 144 + 64 + 16 * h);
          O[0][0] = MFMA32(pa[0][0].s, vb.s, O[0][0]);
          O[1][0] = MFMA32(pa[0][1].s, vb.s, O[1][0]); }
        { U4S8 vb; vb.u = *(const uint4*)(vbb + (32 + l31) * 144 + 64 + 16 * h);
          O[0][1] = MFMA32(pa[0][0].s, vb.s, O[0][1]);
          O[1][1] = MFMA32(pa[0][1].s, vb.s, O[1][1]); }
        { U4S8 vb; vb.u = *(const uint4*)(vbb + l31 * 144 + 96 + 16 * h);
          O[0][0] = MFMA32(pa[1][0].s, vb.s, O[0][0]);
          O[1][0] = MFMA32(pa[1][1].s, vb.s, O[1][0]); }
        { U4S8 vb; vb.u = *(const uint4*)(vbb + (32 + l31) * 144 + 96 + 16 * h);
          O[0][1] = MFMA32(pa[1][0].s, vb.s, O[0][1]);
          O[1][1] = MFMA32(pa[1][1].s, vb.s, O[1][1]); }
    }

    // ---- finalize: L is column-layout (lane l31 holds query 32*mtq+l31);
    //      transpose to O-row layout once via shfls
    float Linv[2];
#pragma unroll
    for (int mtq = 0; mtq < 2; ++mtq) {
        float l = Lsum[mtq] + __shfl_xor(Lsum[mtq], 32, 64);
        Linv[mtq] = 1.0f / l;
    }
    __syncthreads();                          // staging LDS now reusable
    unsigned short* Tw = (unsigned short*)(smem + w * 4608);  // 16 x 72 elems
    unsigned short* aob = aot + ((size_t)bb * NN) * CDIM + hh * 64;
#pragma unroll
    for (int mtq = 0; mtq < 2; ++mtq) {
        float iv[16];
#pragma unroll
        for (int r = 0; r < 16; ++r) {
            int src = (r & 3) + 8 * ((r >> 2) & 1) + 16 * (r >> 3) + 4 * h;
            iv[r] = __shfl(Linv[mtq], src, 64);
        }
#pragma unroll
        for (int rg = 0; rg < 2; ++rg) {      // query sub-block of 16
#pragma unroll
            for (int ntd = 0; ntd < 2; ++ntd)
#pragma unroll
                for (int rr = 0; rr < 8; ++rr) {
                    int r = 8 * rg + rr;
                    int q16 = (rr & 3) + 8 * (rr >> 2) + 4 * h;
                    Tw[q16 * 72 + 32 * ntd + l31] = bf16_1(O[mtq][ntd][r] * iv[r]);
                }
            int row = lane >> 2, cseg = lane & 3;
            uint4 u0 = *(uint4*)(Tw + row * 72 + cseg * 16);
            uint4 u1 = *(uint4*)(Tw + row * 72 + cseg * 16 + 8);
            unsigned short* arow = aob
                + (size_t)(n0w + 32 * mtq + 16 * rg + row) * CDIM + cseg * 16;
            *(uint4*)(arow)     = u0;
            *(uint4*)(arow + 8) = u1;
        }
    }
}

// ------------------------------------------------------- proj MFMA GEMM
__global__ __launch_bounds__(256, 2) void proj_mfma_kernel(
        const unsigned short* __restrict__ aot, const unsigned short* __restrict__ wp,
        float* __restrict__ out) {
    __shared__ unsigned short smem[8192];
    int t = threadIdx.x;
    int lane = t & 63, w = t >> 6;
    int qlo = lane & 15, quad = lane >> 4;
    int b = blockIdx.z, o0 = blockIdx.y * 128, n0 = blockIdx.x * 128;
    const unsigned short* ab = aot + (size_t)b * NN * CDIM;
    int row = t >> 2, seg = t & 3;
    int wn = (w & 1) * 64, wo = (w >> 1) * 64;

    f32x4 acc[4][4];
#pragma unroll
    for (int i = 0; i < 4; ++i)
#pragma unroll
        for (int j = 0; j < 4; ++j) acc[i][j] = f32x4{0.f, 0.f, 0.f, 0.f};

    for (int k0 = 0; k0 < 512; k0 += 32) {
        __syncthreads();
        load_lds16(ab + (size_t)(n0 + row) * 512 + k0 + seg * 8,        smem + t * 8);
        load_lds16(ab + (size_t)(n0 + 64 + row) * 512 + k0 + seg * 8,   smem + 2048 + t * 8);
        load_lds16(wp + (size_t)(o0 + row) * 512 + k0 + seg * 8,        smem + 4096 + t * 8);
        load_lds16(wp + (size_t)(o0 + 64 + row) * 512 + k0 + seg * 8,   smem + 6144 + t * 8);
        __syncthreads();
        U4S8 af[4], bf[4];
#pragma unroll
        for (int mt = 0; mt < 4; ++mt)
            af[mt].u = *(const uint4*)(smem + (wn + 16 * mt + qlo) * 32 + quad * 8);
#pragma unroll
        for (int nt = 0; nt < 4; ++nt)
            bf[nt].u = *(const uint4*)(smem + 4096 + (wo + 16 * nt + qlo) * 32 + quad * 8);
#pragma unroll
        for (int mt = 0; mt < 4; ++mt)
#pragma unroll
            for (int nt = 0; nt < 4; ++nt)
                acc[mt][nt] = __builtin_amdgcn_mfma_f32_16x16x32_bf16(
                    af[mt].s, bf[nt].s, acc[mt][nt], 0, 0, 0);
    }

    float* ob = out + (size_t)b * CDIM * NN;
#pragma unroll
    for (int mt = 0; mt < 4; ++mt)
#pragma unroll
        for (int nt = 0; nt < 4; ++nt) {
            int o = o0 + wo + 16 * nt + qlo;
            int n = n0 + wn + 16 * mt + 4 * quad;
            *(float4*)(ob + (size_t)o * NN + n) = *(float4*)&acc[mt][nt];
        }
}

// ------------------------------------------------------- launch
extern "C" void kernel_launch(void* const* d_in, const int* in_sizes, int n_in,
                              void* d_out, int out_size, void* d_ws, size_t ws_size,
                              hipStream_t stream) {
    const float* x      = (const float*)d_in[0];
    const float* w_qkv  = (const float*)d_in[1];
    const float* w_proj = (const float*)d_in[2];
    float* out = (float*)d_out;
    unsigned short* ws = (unsigned short*)d_ws;

    unsigned short* xt  = ws;                  // bf16 [b][n][c]
    unsigned short* qbf = xt  + QSZ;           // bf16 [bh][n][d]
    unsigned short* kbf = qbf + QSZ;           // bf16 [bh][n][d]
    unsigned short* vt  = kbf + QSZ;           // bf16 [bh][d][n]
    unsigned short* aot = vt  + QSZ;           // bf16 [b][n][c]
    unsigned short* wqb = aot + QSZ;           // bf16 [1536][512]
    unsigned short* wpb = wqb + 786432;        // bf16 [512][512]
    float* ct = (float*)(wpb + 262144);        // [32][4096]
    float* st = ct + 32 * 4096;

    conv_w_kernel<<<512, 256, 0, stream>>>(w_qkv, w_proj, wqb, wpb);
    rope_table_kernel<<<512, 256, 0, stream>>>(ct, st);
    transpose_x_kernel<<<dim3(64, 8, B_), 256, 0, stream>>>(x, xt);
    qkv_mfma_kernel<<<dim3(32, 12, B_), 256, 0, stream>>>(xt, wqb, qbf, kbf, vt, ct, st);
    attn_kernel<<<dim3(NN / 256, HEADS, B_), 256, 0, stream>>>(qbf, kbf, vt, aot);
    proj_mfma_kernel<<<dim3(32, 4, B_), 256, 0, stream>>>(aot, wpb, out);
}

// Round 8
// 278.953 us; speedup vs baseline: 1.0108x; 1.0108x over previous
//
#include <hip/hip_runtime.h>
#include <math.h>

#define B_    4
#define CDIM  512
#define HEADS 8
#define HD    64
#define NN    4096
#define QSZ   ((size_t)B_*HEADS*NN*HD)   // 8388608 elements
// q scale folded with log2(e): 0.125 * 1.4426950408889634
#define SCALE_Q 0.18033688011112042f

typedef __attribute__((ext_vector_type(8))) short short8;   // 8 bf16
typedef __attribute__((ext_vector_type(4))) float f32x4;
typedef __attribute__((ext_vector_type(16))) float f32x16;
union U4S8 { uint4 u; short8 s; };

// RNE fp32 -> bf16
__device__ inline unsigned pk(float a, float b) {
    unsigned ua = __float_as_uint(a), ub = __float_as_uint(b);
    ua += 0x7FFFu + ((ua >> 16) & 1u);
    ub += 0x7FFFu + ((ub >> 16) & 1u);
    return (ua >> 16) | (ub & 0xFFFF0000u);
}
__device__ inline unsigned short bf16_1(float a) {
    unsigned ua = __float_as_uint(a);
    ua += 0x7FFFu + ((ua >> 16) & 1u);
    return (unsigned short)(ua >> 16);
}
// single-instruction packed f32->bf16 (RNE); S0 -> low16, S1 -> high16
__device__ inline unsigned cvtpk(float a, float b) {
    unsigned r;
    asm("v_cvt_pk_bf16_f32 %0, %1, %2" : "=v"(r) : "v"(a), "v"(b));
    return r;
}

__device__ inline void load_lds16(const unsigned short* g, unsigned short* l) {
    __builtin_amdgcn_global_load_lds(
        (const __attribute__((address_space(1))) unsigned int*)g,
        (__attribute__((address_space(3))) unsigned int*)l, 16, 0, 0);
}

// ------------------------------------------------------- weights -> bf16
// wq: 1536x512 (first 512 rows = q, pre-scaled by SCALE_Q); wp: 512x512
__global__ void conv_w_kernel(const float* __restrict__ wq, const float* __restrict__ wp,
                              unsigned short* __restrict__ wqb, unsigned short* __restrict__ wpb) {
    int id = blockIdx.x * 256 + threadIdx.x;
    const float* src; unsigned short* dst; size_t off; float sc = 1.0f;
    if (id < 98304) { src = wq; dst = wqb; off = (size_t)id * 8; if (off < 262144) sc = SCALE_Q; }
    else            { src = wp; dst = wpb; off = (size_t)(id - 98304) * 8; }
    float4 a = *(const float4*)(src + off);
    float4 b = *(const float4*)(src + off + 4);
    uint4 u;
    u.x = pk(a.x * sc, a.y * sc); u.y = pk(a.z * sc, a.w * sc);
    u.z = pk(b.x * sc, b.y * sc); u.w = pk(b.z * sc, b.w * sc);
    *(uint4*)(dst + off) = u;
}

// ------------------------------------------------------- rope tables [j][n]
__global__ void rope_table_kernel(float* __restrict__ ct, float* __restrict__ st) {
    int id = blockIdx.x * 256 + threadIdx.x;
    int j = id >> 12, n = id & 4095;
    int i = j & 15;
    float pos = (j < 16) ? (float)(n >> 6) : (float)(n & 63);
    float freq = exp2f(-(float)i * 0.8304820237218406f);  // 10000^(-i/16)
    float ang = pos * freq;
    ct[id] = cosf(ang);
    st[id] = sinf(ang);
}

// ------------------------------------------------------- x transpose+convert
__global__ __launch_bounds__(256) void transpose_x_kernel(
        const float* __restrict__ x, unsigned short* __restrict__ xt) {
    __shared__ unsigned short T[64 * 72];
    int t = threadIdx.x;
    int b = blockIdx.z, c0 = blockIdx.y * 64, n0 = blockIdx.x * 64;
    const float* xb = x + ((size_t)b * CDIM + c0) * NN + n0;
    int crow = t >> 2, nseg = t & 3;
#pragma unroll
    for (int g = 0; g < 4; ++g) {
        float4 f = *(const float4*)(xb + (size_t)crow * NN + nseg * 16 + g * 4);
        int nb = nseg * 16 + g * 4;
        T[(nb + 0) * 72 + crow] = bf16_1(f.x);
        T[(nb + 1) * 72 + crow] = bf16_1(f.y);
        T[(nb + 2) * 72 + crow] = bf16_1(f.z);
        T[(nb + 3) * 72 + crow] = bf16_1(f.w);
    }
    __syncthreads();
    unsigned short* xo = xt + ((size_t)b * NN + n0) * CDIM + c0;
    int nrow = t >> 2, cseg = t & 3;
    uint4 u0 = *(uint4*)(T + nrow * 72 + cseg * 16);
    uint4 u1 = *(uint4*)(T + nrow * 72 + cseg * 16 + 8);
    *(uint4*)(xo + (size_t)nrow * CDIM + cseg * 16)     = u0;
    *(uint4*)(xo + (size_t)nrow * CDIM + cseg * 16 + 8) = u1;
}

// ------------------------------------------------------- qkv MFMA GEMM
__global__ __launch_bounds__(256, 2) void qkv_mfma_kernel(
        const unsigned short* __restrict__ xt, const unsigned short* __restrict__ wq,
        unsigned short* __restrict__ qbf, unsigned short* __restrict__ kbf,
        unsigned short* __restrict__ vt,
        const float* __restrict__ ct, const float* __restrict__ st) {
    __shared__ unsigned short smem[8192];
    int t = threadIdx.x;
    int lane = t & 63, w = t >> 6;
    int qlo = lane & 15, quad = lane >> 4;
    int b = blockIdx.z, o0 = blockIdx.y * 128, n0 = blockIdx.x * 128;
    const unsigned short* xb = xt + (size_t)b * NN * CDIM;
    int row = t >> 2, seg = t & 3;
    int wn = (w & 1) * 64, wo = (w >> 1) * 64;

    f32x4 acc[4][4];
#pragma unroll
    for (int i = 0; i < 4; ++i)
#pragma unroll
        for (int j = 0; j < 4; ++j) acc[i][j] = f32x4{0.f, 0.f, 0.f, 0.f};

    for (int k0 = 0; k0 < 512; k0 += 32) {
        __syncthreads();
        load_lds16(xb + (size_t)(n0 + row) * 512 + k0 + seg * 8,        smem + t * 8);
        load_lds16(xb + (size_t)(n0 + 64 + row) * 512 + k0 + seg * 8,   smem + 2048 + t * 8);
        load_lds16(wq + (size_t)(o0 + row) * 512 + k0 + seg * 8,        smem + 4096 + t * 8);
        load_lds16(wq + (size_t)(o0 + 64 + row) * 512 + k0 + seg * 8,   smem + 6144 + t * 8);
        __syncthreads();
        U4S8 af[4], bf[4];
#pragma unroll
        for (int mt = 0; mt < 4; ++mt)
            af[mt].u = *(const uint4*)(smem + (wn + 16 * mt + qlo) * 32 + quad * 8);
#pragma unroll
        for (int nt = 0; nt < 4; ++nt)
            bf[nt].u = *(const uint4*)(smem + 4096 + (wo + 16 * nt + qlo) * 32 + quad * 8);
#pragma unroll
        for (int mt = 0; mt < 4; ++mt)
#pragma unroll
            for (int nt = 0; nt < 4; ++nt)
                acc[mt][nt] = __builtin_amdgcn_mfma_f32_16x16x32_bf16(
                    af[mt].s, bf[nt].s, acc[mt][nt], 0, 0, 0);
    }

    int og = o0 + wo;
    int s = og >> 9;
    int h = (og & 511) >> 6;
    int bh = b * HEADS + h;
    if (s < 2) {
        unsigned short* dst = (s ? kbf : qbf) + (size_t)bh * NN * HD;
#pragma unroll
        for (int mt = 0; mt < 4; ++mt) {
            int nbase = n0 + wn + 16 * mt + 4 * quad;
#pragma unroll
            for (int ntp = 0; ntp < 2; ++ntp) {
                int j = 16 * ntp + qlo;
                float4 c4 = *(const float4*)(ct + (size_t)j * NN + nbase);
                float4 s4 = *(const float4*)(st + (size_t)j * NN + nbase);
                float cc[4] = {c4.x, c4.y, c4.z, c4.w};
                float ss[4] = {s4.x, s4.y, s4.z, s4.w};
#pragma unroll
                for (int r = 0; r < 4; ++r) {
                    float x1 = acc[mt][ntp][r], x2 = acc[mt][ntp + 2][r];
                    size_t base = (size_t)(nbase + r) * HD;
                    dst[base + j]      = bf16_1(x1 * cc[r] - x2 * ss[r]);
                    dst[base + j + 32] = bf16_1(x1 * ss[r] + x2 * cc[r]);
                }
            }
        }
    } else {
        unsigned short* dst = vt + (size_t)bh * HD * NN;
#pragma unroll
        for (int mt = 0; mt < 4; ++mt)
#pragma unroll
            for (int nt = 0; nt < 4; ++nt) {
                int d = 16 * nt + qlo;
                int n = n0 + wn + 16 * mt + 4 * quad;
                uint2 u;
                u.x = pk(acc[mt][nt][0], acc[mt][nt][1]);
                u.y = pk(acc[mt][nt][2], acc[mt][nt][3]);
                *(uint2*)(dst + (size_t)d * NN + n) = u;
            }
    }
}

// exp2 + pack one 8-value group of an S tile into a PV A-frag, accumulating L
#define EXP_GRP(Sv, MTQ, KSL, PA)                                        \
    {                                                                    \
        float p0 = __builtin_amdgcn_exp2f(Sv[8 * (KSL) + 0]);            \
        float p1 = __builtin_amdgcn_exp2f(Sv[8 * (KSL) + 1]);            \
        float p2 = __builtin_amdgcn_exp2f(Sv[8 * (KSL) + 2]);            \
        float p3 = __builtin_amdgcn_exp2f(Sv[8 * (KSL) + 3]);            \
        float p4 = __builtin_amdgcn_exp2f(Sv[8 * (KSL) + 4]);            \
        float p5 = __builtin_amdgcn_exp2f(Sv[8 * (KSL) + 5]);            \
        float p6 = __builtin_amdgcn_exp2f(Sv[8 * (KSL) + 6]);            \
        float p7 = __builtin_amdgcn_exp2f(Sv[8 * (KSL) + 7]);            \
        Lsum[MTQ] += ((p0 + p1) + (p2 + p3)) + ((p4 + p5) + (p6 + p7));  \
        PA.u.x = cvtpk(p0, p1); PA.u.y = cvtpk(p2, p3);                  \
        PA.u.z = cvtpk(p4, p5); PA.u.w = cvtpk(p6, p7);                  \
    }

#define MFMA32(A, B, C) __builtin_amdgcn_mfma_f32_32x32x16_bf16((A), (B), (C), 0, 0, 0)

// pipeline half-step with register prefetch: all ds_reads issue at the TOP
// (vb for PV(s-1): ~1000cyc cover under QK+exp; KAN = ka for subtile s+1:
// ~full-half-step cover).  QK(s) consumes the preloaded KAC; PV(s-1)
// consumes the vb loaded at the top of THIS step.  No lgkm wait sits
// directly before any MFMA in steady state.
#define HALF_STEP_PF(SCONS, SPROD, KAC, KAN, KN_B, KN_H, VB_B, V_H)                      \
    {                                                                                    \
        U4S8 vb0, vb1, vb2, vb3;                                                         \
        vb0.u = *(const uint4*)((VB_B) + l31 * 144 + (V_H) * 64 + 16 * h);               \
        vb1.u = *(const uint4*)((VB_B) + (32 + l31) * 144 + (V_H) * 64 + 16 * h);        \
        vb2.u = *(const uint4*)((VB_B) + l31 * 144 + (V_H) * 64 + 32 + 16 * h);          \
        vb3.u = *(const uint4*)((VB_B) + (32 + l31) * 144 + (V_H) * 64 + 32 + 16 * h);   \
        KAN[0].u = *(const uint4*)((KN_B) + ((KN_H) * 32 + l31) * 144 + 16 * h);         \
        KAN[1].u = *(const uint4*)((KN_B) + ((KN_H) * 32 + l31) * 144 + 32 + 16 * h);    \
        KAN[2].u = *(const uint4*)((KN_B) + ((KN_H) * 32 + l31) * 144 + 64 + 16 * h);    \
        KAN[3].u = *(const uint4*)((KN_B) + ((KN_H) * 32 + l31) * 144 + 96 + 16 * h);    \
        U4S8 pa[2][2];                                                                   \
        SPROD[0] = MFMA32(KAC[0].s, qf[0][0].s, Zv);                                     \
        SPROD[1] = MFMA32(KAC[0].s, qf[1][0].s, Zv);                                     \
        EXP_GRP(SCONS[0], 0, 0, pa[0][0]);                                               \
        SPROD[0] = MFMA32(KAC[1].s, qf[0][1].s, SPROD[0]);                               \
        SPROD[1] = MFMA32(KAC[1].s, qf[1][1].s, SPROD[1]);                               \
        EXP_GRP(SCONS[0], 0, 1, pa[1][0]);                                               \
        SPROD[0] = MFMA32(KAC[2].s, qf[0][2].s, SPROD[0]);                               \
        SPROD[1] = MFMA32(KAC[2].s, qf[1][2].s, SPROD[1]);                               \
        EXP_GRP(SCONS[1], 1, 0, pa[0][1]);                                               \
        SPROD[0] = MFMA32(KAC[3].s, qf[0][3].s, SPROD[0]);                               \
        SPROD[1] = MFMA32(KAC[3].s, qf[1][3].s, SPROD[1]);                               \
        EXP_GRP(SCONS[1], 1, 1, pa[1][1]);                                               \
        O[0][0] = MFMA32(pa[0][0].s, vb0.s, O[0][0]);                                    \
        O[1][0] = MFMA32(pa[0][1].s, vb0.s, O[1][0]);                                    \
        O[0][1] = MFMA32(pa[0][0].s, vb1.s, O[0][1]);                                    \
        O[1][1] = MFMA32(pa[0][1].s, vb1.s, O[1][1]);                                    \
        O[0][0] = MFMA32(pa[1][0].s, vb2.s, O[0][0]);                                    \
        O[1][0] = MFMA32(pa[1][1].s, vb2.s, O[1][0]);                                    \
        O[0][1] = MFMA32(pa[1][0].s, vb3.s, O[0][1]);                                    \
        O[1][1] = MFMA32(pa[1][1].s, vb3.s, O[1][1]);                                    \
    }

// ------------------------------------------------------- attention (MFMA bf16, 32x32x16)
// Triple-buffered K/V LDS, cross-subtile 2-deep pipeline, and REGISTER
// PREFETCH of all LDS operands: ka double-buffered across half-steps
// (kaA/kaB), vb hoisted to the top of each half-step.  In steady state no
// MFMA has an lgkm wait in front of it, so a wave keeps issuing exp2/cvtpk
// under MFMA execution.  One barrier per 64-key tile.
// Sᵀ=K·Qᵀ; the 32x32 C-layout doubles as the PV A-layout under the key
// permutation "swap bits 2<->3" applied to V at LDS staging.  cvt_pk packs
// P straight into PV A-frags; L on VALU; column-layout L transposed once
// via shfls in the epilogue.  exp2 softmax (log2e folded into q).
// LDS 55296 B.
__global__ __launch_bounds__(256, 2) void attn_kernel(
        const unsigned short* __restrict__ qbf, const unsigned short* __restrict__ kbf,
        const unsigned short* __restrict__ vt, unsigned short* __restrict__ aot) {
    __shared__ unsigned char smem[55296];     // 3 x (K 64x144 | V 64x144)
    int t = threadIdx.x;
    int lane = t & 63, w = t >> 6;
    int l31 = lane & 31, h = lane >> 5;
    int bb = blockIdx.z, hh = blockIdx.y;
    int bh = bb * HEADS + hh;
    int n0w = blockIdx.x * 256 + w * 64;

    // Q B-frags: qf[mtq][ks]  (col=query=l31, k = 16*ks + 8*h + j)
    U4S8 qf[2][4];
    const unsigned short* qg = qbf + ((size_t)bh * NN + n0w) * HD;
#pragma unroll
    for (int mtq = 0; mtq < 2; ++mtq)
#pragma unroll
        for (int ks = 0; ks < 4; ++ks)
            qf[mtq][ks].u = *(const uint4*)(qg + (size_t)(32 * mtq + l31) * 64 + 16 * ks + 8 * h);

    f32x16 Zv;
#pragma unroll
    for (int i = 0; i < 16; ++i) Zv[i] = 0.f;

    f32x16 O[2][2];
#pragma unroll
    for (int mtq = 0; mtq < 2; ++mtq)
#pragma unroll
        for (int ntd = 0; ntd < 2; ++ntd) O[mtq][ntd] = Zv;
    float Lsum[2] = {0.f, 0.f};              // column sum for query 32*mtq + l31

    const uint4* kg = (const uint4*)kbf + (size_t)bh * NN * 8;
    const uint4* vg = (const uint4*)vt  + (size_t)bh * 64 * 512;

    int rr0 = t >> 3, s8 = t & 7;            // K row / V d-row 0..31 (+32 for second)
    // V permuted in-row byte offset: key-bit2<->bit3 swap at quad granularity
    int voff = 32 * (s8 >> 1) + 8 * (s8 & 1);

    // incremented global pointers (tile stride: K 512 uint4, V 8 uint4)
    const uint4* kp0 = kg + rr0 * 8 + s8;
    const uint4* kp1 = kg + (32 + rr0) * 8 + s8;
    const uint4* vp0 = vg + rr0 * 512 + s8;
    const uint4* vp1 = vg + (32 + rr0) * 512 + s8;

    // per-thread LDS staging destinations (within a buffer)
    unsigned char* kd0 = smem + rr0 * 144 + s8 * 16;
    unsigned char* kd1 = smem + (32 + rr0) * 144 + s8 * 16;
    unsigned char* vd0 = smem + 9216 + rr0 * 144 + voff;
    unsigned char* vd1 = smem + 9216 + (32 + rr0) * 144 + voff;

    // prologue: tiles 0,1 -> buf0,buf1; tile 2 -> regs
    uint4 kr0, kr1, vr0, vr1;
#pragma unroll
    for (int pt = 0; pt < 2; ++pt) {
        kr0 = kp0[0]; kr1 = kp1[0]; vr0 = vp0[0]; vr1 = vp1[0];
        kp0 += 512; kp1 += 512; vp0 += 8; vp1 += 8;
        int bo = pt * 18432;
        *(uint4*)(kd0 + bo) = kr0;
        *(uint4*)(kd1 + bo) = kr1;
        *(uint2*)(vd0 + bo)      = make_uint2(vr0.x, vr0.y);
        *(uint2*)(vd0 + bo + 16) = make_uint2(vr0.z, vr0.w);
        *(uint2*)(vd1 + bo)      = make_uint2(vr1.x, vr1.y);
        *(uint2*)(vd1 + bo + 16) = make_uint2(vr1.z, vr1.w);
    }
    kr0 = kp0[0]; kr1 = kp1[0]; vr0 = vp0[0]; vr1 = vp1[0];
    kp0 += 512; kp1 += 512; vp0 += 8; vp1 += 8;
    __syncthreads();

    // prime: QK(subtile 0) -> SB  (buf0, khalf 0); kaA <- K(subtile 1)
    f32x16 SA[2], SB[2];
    U4S8 kaA[4], kaB[4];
    {
        U4S8 ka0, ka1, ka2, ka3;
        ka0.u = *(const uint4*)(smem + l31 * 144 + 16 * h);
        ka1.u = *(const uint4*)(smem + l31 * 144 + 32 + 16 * h);
        ka2.u = *(const uint4*)(smem + l31 * 144 + 64 + 16 * h);
        ka3.u = *(const uint4*)(smem + l31 * 144 + 96 + 16 * h);
        kaA[0].u = *(const uint4*)(smem + (32 + l31) * 144 + 16 * h);
        kaA[1].u = *(const uint4*)(smem + (32 + l31) * 144 + 32 + 16 * h);
        kaA[2].u = *(const uint4*)(smem + (32 + l31) * 144 + 64 + 16 * h);
        kaA[3].u = *(const uint4*)(smem + (32 + l31) * 144 + 96 + 16 * h);
        SB[0] = MFMA32(ka0.s, qf[0][0].s, Zv);
        SB[1] = MFMA32(ka0.s, qf[1][0].s, Zv);
        SB[0] = MFMA32(ka1.s, qf[0][1].s, SB[0]);
        SB[1] = MFMA32(ka1.s, qf[1][1].s, SB[1]);
        SB[0] = MFMA32(ka2.s, qf[0][2].s, SB[0]);
        SB[1] = MFMA32(ka2.s, qf[1][2].s, SB[1]);
        SB[0] = MFMA32(ka3.s, qf[0][3].s, SB[0]);
        SB[1] = MFMA32(ka3.s, qf[1][3].s, SB[1]);
    }

    int b0 = 0, b1 = 18432, b2 = 36864;      // rotating buffer byte offsets
    for (int c = 0; c < 63; ++c) {
        // ---- stage tile c+2 (in regs) -> buf b2; issue loads for tile c+3
        // (over-reads past the KV stream stay inside the workspace - harmless)
        *(uint4*)(kd0 + b2) = kr0;
        *(uint4*)(kd1 + b2) = kr1;
        *(uint2*)(vd0 + b2)      = make_uint2(vr0.x, vr0.y);
        *(uint2*)(vd0 + b2 + 16) = make_uint2(vr0.z, vr0.w);
        *(uint2*)(vd1 + b2)      = make_uint2(vr1.x, vr1.y);
        *(uint2*)(vd1 + b2 + 16) = make_uint2(vr1.z, vr1.w);
        kr0 = kp0[0]; kr1 = kp1[0]; vr0 = vp0[0]; vr1 = vp1[0];
        kp0 += 512; kp1 += 512; vp0 += 8; vp1 += 8;

        __builtin_amdgcn_s_setprio(1);
        // step1 (subtile 2c+1): QK w/ kaA | exp(S(2c)=SB) | PV(2c) w/ V(b0,h0);
        //                       loads kaB <- K(2c+2) [b1 half0]
        HALF_STEP_PF(SB, SA, kaA, kaB, smem + b1, 0, smem + b0 + 9216, 0)
        // step2 (subtile 2c+2): QK w/ kaB | exp(S(2c+1)=SA) | PV(2c+1) w/ V(b0,h1);
        //                       loads kaA <- K(2c+3) [b1 half1]
        HALF_STEP_PF(SA, SB, kaB, kaA, smem + b1, 1, smem + b0 + 9216, 1)
        __builtin_amdgcn_s_setprio(0);

        int tmp = b0; b0 = b1; b1 = b2; b2 = tmp;
        __syncthreads();
    }

    // epilogue: subtile 127 (kaA holds K(127); b0 = tile 63 after rotation)
    {
        U4S8 vb0, vb1, vb2, vb3;
        const unsigned char* vbb = smem + b0 + 9216;
        vb0.u = *(const uint4*)(vbb + l31 * 144 + 16 * h);
        vb1.u = *(const uint4*)(vbb + (32 + l31) * 144 + 16 * h);
        vb2.u = *(const uint4*)(vbb + l31 * 144 + 32 + 16 * h);
        vb3.u = *(const uint4*)(vbb + (32 + l31) * 144 + 32 + 16 * h);
        U4S8 pa[2][2];
        SA[0] = MFMA32(kaA[0].s, qf[0][0].s, Zv);
        SA[1] = MFMA32(kaA[0].s, qf[1][0].s, Zv);
        EXP_GRP(SB[0], 0, 0, pa[0][0]);
        SA[0] = MFMA32(kaA[1].s, qf[0][1].s, SA[0]);
        SA[1] = MFMA32(kaA[1].s, qf[1][1].s, SA[1]);
        EXP_GRP(SB[0], 0, 1, pa[1][0]);
        SA[0] = MFMA32(kaA[2].s, qf[0][2].s, SA[0]);
        SA[1] = MFMA32(kaA[2].s, qf[1][2].s, SA[1]);
        EXP_GRP(SB[1], 1, 0, pa[0][1]);
        SA[0] = MFMA32(kaA[3].s, qf[0][3].s, SA[0]);
        SA[1] = MFMA32(kaA[3].s, qf[1][3].s, SA[1]);
        EXP_GRP(SB[1], 1, 1, pa[1][1]);
        O[0][0] = MFMA32(pa[0][0].s, vb0.s, O[0][0]);
        O[1][0] = MFMA32(pa[0][1].s, vb0.s, O[1][0]);
        O[0][1] = MFMA32(pa[0][0].s, vb1.s, O[0][1]);
        O[1][1] = MFMA32(pa[0][1].s, vb1.s, O[1][1]);
        O[0][0] = MFMA32(pa[1][0].s, vb2.s, O[0][0]);
        O[1][0] = MFMA32(pa[1][1].s, vb2.s, O[1][0]);
        O[0][1] = MFMA32(pa[1][0].s, vb3.s, O[0][1]);
        O[1][1] = MFMA32(pa[1][1].s, vb3.s, O[1][1]);
    }
    // final: exp(S(127)=SA) + PV(127), V buf b0 half 1
    {
        U4S8 pa[2][2];
        EXP_GRP(SA[0], 0, 0, pa[0][0]);
        EXP_GRP(SA[0], 0, 1, pa[1][0]);
        EXP_GRP(SA[1], 1, 0, pa[0][1]);
        EXP_GRP(SA[1], 1, 1, pa[1][1]);
        const unsigned char* vbb = smem + b0 + 9216;
        { U4S8 vb; vb.u = *(const uint4*)(vbb + l31 * 144 + 64 + 16 * h);
          O[0][0] = MFMA32(pa[0][0].s, vb.s, O[0][0]);
          O[1][0] = MFMA32(pa[0][1].s, vb.s, O[1][0]); }
        { U4S8 vb; vb.u = *(const uint4*)(vbb + (32 + l31) * 144 + 64 + 16 * h);
          O[0][1] = MFMA32(pa[0][0].s, vb.s, O[0][1]);
          O[1][1] = MFMA32(pa[0][1].s, vb.s, O[1][1]); }
        { U4S8 vb; vb.u = *(const uint4*)(vbb + l31 * 144 + 96 + 16 * h);
          O[0][0] = MFMA32(pa[1][0].s, vb.s, O[0][0]);
          O[1][0] = MFMA32(pa[1][1].s, vb.s, O[1][0]); }
        { U4S8 vb; vb.u = *(const uint4*)(vbb + (32 + l31) * 144 + 96 + 16 * h);
          O[0][1] = MFMA32(pa[1][0].s, vb.s, O[0][1]);
          O[1][1] = MFMA32(pa[1][1].s, vb.s, O[1][1]); }
    }

    // ---- finalize: L is column-layout (lane l31 holds query 32*mtq+l31);
    //      transpose to O-row layout once via shfls
    float Linv[2];
#pragma unroll
    for (int mtq = 0; mtq < 2; ++mtq) {
        float l = Lsum[mtq] + __shfl_xor(Lsum[mtq], 32, 64);
        Linv[mtq] = 1.0f / l;
    }
    __syncthreads();                          // staging LDS now reusable
    unsigned short* Tw = (unsigned short*)(smem + w * 4608);  // 16 x 72 elems
    unsigned short* aob = aot + ((size_t)bb * NN) * CDIM + hh * 64;
#pragma unroll
    for (int mtq = 0; mtq < 2; ++mtq) {
        float iv[16];
#pragma unroll
        for (int r = 0; r < 16; ++r) {
            int src = (r & 3) + 8 * ((r >> 2) & 1) + 16 * (r >> 3) + 4 * h;
            iv[r] = __shfl(Linv[mtq], src, 64);
        }
#pragma unroll
        for (int rg = 0; rg < 2; ++rg) {      // query sub-block of 16
#pragma unroll
            for (int ntd = 0; ntd < 2; ++ntd)
#pragma unroll
                for (int rr = 0; rr < 8; ++rr) {
                    int r = 8 * rg + rr;
                    int q16 = (rr & 3) + 8 * (rr >> 2) + 4 * h;
                    Tw[q16 * 72 + 32 * ntd + l31] = bf16_1(O[mtq][ntd][r] * iv[r]);
                }
            int row = lane >> 2, cseg = lane & 3;
            uint4 u0 = *(uint4*)(Tw + row * 72 + cseg * 16);
            uint4 u1 = *(uint4*)(Tw + row * 72 + cseg * 16 + 8);
            unsigned short* arow = aob
                + (size_t)(n0w + 32 * mtq + 16 * rg + row) * CDIM + cseg * 16;
            *(uint4*)(arow)     = u0;
            *(uint4*)(arow + 8) = u1;
        }
    }
}

// ------------------------------------------------------- proj MFMA GEMM
__global__ __launch_bounds__(256, 2) void proj_mfma_kernel(
        const unsigned short* __restrict__ aot, const unsigned short* __restrict__ wp,
        float* __restrict__ out) {
    __shared__ unsigned short smem[8192];
    int t = threadIdx.x;
    int lane = t & 63, w = t >> 6;
    int qlo = lane & 15, quad = lane >> 4;
    int b = blockIdx.z, o0 = blockIdx.y * 128, n0 = blockIdx.x * 128;
    const unsigned short* ab = aot + (size_t)b * NN * CDIM;
    int row = t >> 2, seg = t & 3;
    int wn = (w & 1) * 64, wo = (w >> 1) * 64;

    f32x4 acc[4][4];
#pragma unroll
    for (int i = 0; i < 4; ++i)
#pragma unroll
        for (int j = 0; j < 4; ++j) acc[i][j] = f32x4{0.f, 0.f, 0.f, 0.f};

    for (int k0 = 0; k0 < 512; k0 += 32) {
        __syncthreads();
        load_lds16(ab + (size_t)(n0 + row) * 512 + k0 + seg * 8,        smem + t * 8);
        load_lds16(ab + (size_t)(n0 + 64 + row) * 512 + k0 + seg * 8,   smem + 2048 + t * 8);
        load_lds16(wp + (size_t)(o0 + row) * 512 + k0 + seg * 8,        smem + 4096 + t * 8);
        load_lds16(wp + (size_t)(o0 + 64 + row) * 512 + k0 + seg * 8,   smem + 6144 + t * 8);
        __syncthreads();
        U4S8 af[4], bf[4];
#pragma unroll
        for (int mt = 0; mt < 4; ++mt)
            af[mt].u = *(const uint4*)(smem + (wn + 16 * mt + qlo) * 32 + quad * 8);
#pragma unroll
        for (int nt = 0; nt < 4; ++nt)
            bf[nt].u = *(const uint4*)(smem + 4096 + (wo + 16 * nt + qlo) * 32 + quad * 8);
#pragma unroll
        for (int mt = 0; mt < 4; ++mt)
#pragma unroll
            for (int nt = 0; nt < 4; ++nt)
                acc[mt][nt] = __builtin_amdgcn_mfma_f32_16x16x32_bf16(
                    af[mt].s, bf[nt].s, acc[mt][nt], 0, 0, 0);
    }

    float* ob = out + (size_t)b * CDIM * NN;
#pragma unroll
    for (int mt = 0; mt < 4; ++mt)
#pragma unroll
        for (int nt = 0; nt < 4; ++nt) {
            int o = o0 + wo + 16 * nt + qlo;
            int n = n0 + wn + 16 * mt + 4 * quad;
            *(float4*)(ob + (size_t)o * NN + n) = *(float4*)&acc[mt][nt];
        }
}

// ------------------------------------------------------- launch
extern "C" void kernel_launch(void* const* d_in, const int* in_sizes, int n_in,
                              void* d_out, int out_size, void* d_ws, size_t ws_size,
                              hipStream_t stream) {
    const float* x      = (const float*)d_in[0];
    const float* w_qkv  = (const float*)d_in[1];
    const float* w_proj = (const float*)d_in[2];
    float* out = (float*)d_out;
    unsigned short* ws = (unsigned short*)d_ws;

    unsigned short* xt  = ws;                  // bf16 [b][n][c]
    unsigned short* qbf = xt  + QSZ;           // bf16 [bh][n][d]
    unsigned short* kbf = qbf + QSZ;           // bf16 [bh][n][d]
    unsigned short* vt  = kbf + QSZ;           // bf16 [bh][d][n]
    unsigned short* aot = vt  + QSZ;           // bf16 [b][n][c]
    unsigned short* wqb = aot + QSZ;           // bf16 [1536][512]
    unsigned short* wpb = wqb + 786432;        // bf16 [512][512]
    float* ct = (float*)(wpb + 262144);        // [32][4096]
    float* st = ct + 32 * 4096;

    conv_w_kernel<<<512, 256, 0, stream>>>(w_qkv, w_proj, wqb, wpb);
    rope_table_kernel<<<512, 256, 0, stream>>>(ct, st);
    transpose_x_kernel<<<dim3(64, 8, B_), 256, 0, stream>>>(x, xt);
    qkv_mfma_kernel<<<dim3(32, 12, B_), 256, 0, stream>>>(xt, wqb, qbf, kbf, vt, ct, st);
    attn_kernel<<<dim3(NN / 256, HEADS, B_), 256, 0, stream>>>(qbf, kbf, vt, aot);
    proj_mfma_kernel<<<dim3(32, 4, B_), 256, 0, stream>>>(aot, wpb, out);
}